// Round 2
// baseline (214.980 us; speedup 1.0000x reference)
//
#include <hip/hip_runtime.h>
#include <hip/hip_bf16.h>

// Bahdanau additive attention, fp32.
// query [TQ,B,D], value [TV,B,D], mask [TV,B] (int), W1 [D,U], W2 [D,U], scale [U]
// out [TQ,B,D]
// TQ=256, TV=1024, B=4, D=128, U=128

#define TQ 256
#define TV 1024
#define BB 4
#define DD 128
#define UU 128

__device__ __forceinline__ float fast_tanh(float x) {
    // tanh(x) = 1 - 2/(exp(2x)+1); clamp to avoid inf/inf
    x = fminf(fmaxf(x, -15.f), 15.f);
    float e = __expf(2.f * x);
    return 1.f - 2.f * __builtin_amdgcn_rcpf(e + 1.f);
}

// out[b][t][U] = X[t][b][:] @ W  (X: [T,B,D], W: [D,U])
__global__ __launch_bounds__(128) void proj_kernel(
    const float* __restrict__ X, const float* __restrict__ W,
    float* __restrict__ out, int T)
{
    int tb = blockIdx.x;          // t*B + b
    int t = tb / BB, b = tb % BB;
    int u = threadIdx.x;

    __shared__ float xs[DD];
    xs[u] = X[(size_t)(t * BB + b) * DD + u];
    __syncthreads();

    float acc = 0.f;
#pragma unroll 8
    for (int d = 0; d < DD; ++d)
        acc += xs[d] * W[d * UU + u];

    out[((size_t)b * T + t) * UU + u] = acc;
}

__global__ __launch_bounds__(256) void attn_kernel(
    const float* __restrict__ value,  // [TV, B, D]
    const int*   __restrict__ mask,   // [TV, B]
    const float* __restrict__ scale,  // [U]
    const float* __restrict__ wq,     // [B, TQ, U]
    const float* __restrict__ wk,     // [B, TV, U]
    float* __restrict__ out)          // [TQ, B, D]
{
    const int bq = blockIdx.x;
    const int b = bq / TQ;
    const int q = bq % TQ;
    const int t = threadIdx.x;
    const int lane = t & 63;
    const int wid = t >> 6;

    __shared__ float wq_lds[UU];
    __shared__ float sc_lds[UU];
    __shared__ float attn_lds[TV];
    __shared__ float red[8];
    __shared__ float part[DD];

    if (t < UU) {
        wq_lds[t] = wq[((size_t)b * TQ + q) * UU + t];
        sc_lds[t] = scale[t];
    }
    __syncthreads();

    // ---- scores: each thread computes 4 score values (v = t + 256*j) ----
    float s[4];
    const float4* wq4 = (const float4*)wq_lds;
    const float4* sc4 = (const float4*)sc_lds;
#pragma unroll
    for (int j = 0; j < 4; ++j) {
        int v = t + j * 256;
        const float4* wkrow = (const float4*)(wk + ((size_t)b * TV + v) * UU);
        float acc = 0.f;
#pragma unroll
        for (int uu = 0; uu < UU / 4; ++uu) {
            float4 a = wkrow[uu];
            float4 c = wq4[uu];
            float4 sv = sc4[uu];
            acc += sv.x * fast_tanh(a.x + c.x);
            acc += sv.y * fast_tanh(a.y + c.y);
            acc += sv.z * fast_tanh(a.z + c.z);
            acc += sv.w * fast_tanh(a.w + c.w);
        }
        s[j] = mask[v * BB + b] ? acc : -1e9f;
    }

    // ---- softmax over the 1024 scores of this (b,q) row ----
    float m = fmaxf(fmaxf(s[0], s[1]), fmaxf(s[2], s[3]));
#pragma unroll
    for (int off = 32; off > 0; off >>= 1)
        m = fmaxf(m, __shfl_xor(m, off, 64));
    if (lane == 0) red[wid] = m;
    __syncthreads();
    m = fmaxf(fmaxf(red[0], red[1]), fmaxf(red[2], red[3]));

    float p[4], psum = 0.f;
#pragma unroll
    for (int j = 0; j < 4; ++j) {
        p[j] = __expf(s[j] - m);
        psum += p[j];
    }
#pragma unroll
    for (int off = 32; off > 0; off >>= 1)
        psum += __shfl_xor(psum, off, 64);
    if (lane == 0) red[4 + wid] = psum;
    __syncthreads();
    float total = red[4] + red[5] + red[6] + red[7];
    float inv = 1.f / total;

#pragma unroll
    for (int j = 0; j < 4; ++j)
        attn_lds[t + j * 256] = p[j] * inv;
    __syncthreads();

    // ---- context: out[q,b,d] = sum_v attn[v] * value[v,b,d] ----
    const int half = t >> 7;      // 0: v in [0,512), 1: v in [512,1024)
    const int d = t & 127;
    float acc = 0.f;
    const int v0 = half * 512;
#pragma unroll 4
    for (int v = v0; v < v0 + 512; ++v)
        acc += attn_lds[v] * value[((size_t)v * BB + b) * DD + d];

    if (half == 1) part[d] = acc;
    __syncthreads();
    if (half == 0)
        out[((size_t)q * BB + b) * DD + d] = acc + part[d];
}

extern "C" void kernel_launch(void* const* d_in, const int* in_sizes, int n_in,
                              void* d_out, int out_size, void* d_ws, size_t ws_size,
                              hipStream_t stream) {
    const float* query = (const float*)d_in[0];  // [TQ,B,D]
    const float* value = (const float*)d_in[1];  // [TV,B,D]
    const int*   mask  = (const int*)  d_in[2];  // [TV,B]
    const float* W1    = (const float*)d_in[3];  // [D,U]
    const float* W2    = (const float*)d_in[4];  // [D,U]
    const float* scale = (const float*)d_in[5];  // [U]
    float* out = (float*)d_out;

    float* wq = (float*)d_ws;                        // [B,TQ,U] = 131072 floats
    float* wk = wq + (size_t)BB * TQ * UU;           // [B,TV,U] = 524288 floats

    proj_kernel<<<TQ * BB, 128, 0, stream>>>(query, W1, wq, TQ);
    proj_kernel<<<TV * BB, 128, 0, stream>>>(value, W2, wk, TV);
    attn_kernel<<<BB * TQ, 256, 0, stream>>>(value, mask, scale, wq, wk, out);
}

// Round 3
// 75.273 us; speedup vs baseline: 2.8560x; 2.8560x over previous
//
#include <hip/hip_runtime.h>

// Bahdanau additive attention, fp32.
// query [TQ,B,D], value [TV,B,D], mask [TV,B] (int), W1 [D,U], W2 [D,U], scale [U]
// out [TQ,B,D]

#define TQ 256
#define TV 1024
#define BB 4
#define DD 128
#define UU 128
#define NEG_INF -1e9f

__device__ __forceinline__ float fast_tanh(float x) {
    // tanh(x) = 1 - 2/(exp(2x)+1). Inf-safe without clamp:
    // e=+inf -> rcp(inf)=0 -> 1;  e=0 -> rcp(1)=1 -> -1.
    float e = __expf(2.f * x);
    return __builtin_fmaf(-2.f, __builtin_amdgcn_rcpf(e + 1.f), 1.f);
}

// out[b][t][U] = X[t][b][:] @ W  (X: [T,B,D], W: [D,U])
__global__ __launch_bounds__(128) void proj_kernel(
    const float* __restrict__ X, const float* __restrict__ W,
    float* __restrict__ out, int T)
{
    int tb = blockIdx.x;          // t*B + b
    int t = tb / BB, b = tb % BB;
    int u = threadIdx.x;

    __shared__ float xs[DD];
    xs[u] = X[(size_t)(t * BB + b) * DD + u];
    __syncthreads();

    float acc = 0.f;
#pragma unroll 8
    for (int d = 0; d < DD; ++d)
        acc += xs[d] * W[d * UU + u];

    out[((size_t)b * T + t) * UU + u] = acc;
}

// One score per thread. Block = 8 q x 32 v tile for one b.
// Grid: (TV/32, TQ/8, B) = (32, 32, 4) = 4096 blocks.
__global__ __launch_bounds__(256) void scores_kernel(
    const float* __restrict__ wq,     // [B,TQ,U]
    const float* __restrict__ wk,     // [B,TV,U]
    const float* __restrict__ scale,  // [U]
    const int*   __restrict__ mask,   // [TV,B]
    float* __restrict__ scores)       // [B,TQ,TV]
{
    const int b  = blockIdx.z;
    const int q0 = blockIdx.y * 8;
    const int v0 = blockIdx.x * 32;
    const int t  = threadIdx.x;

    __shared__ float4 wq_lds[8][33];   // +1 f4 pad
    __shared__ float4 wk_lds[32][33];  // cols XOR-swizzled by (row>>3)
    __shared__ float4 sc_lds[32];

    // stage wq tile: 8 rows x 32 f4, one f4 per thread, coalesced
    {
        const float4* g = (const float4*)wq;
        int r = t >> 5, c = t & 31;
        wq_lds[r][c] = g[((size_t)(b * TQ + q0 + r)) * 32 + c];
        if (t < 32) sc_lds[t] = ((const float4*)scale)[t];
    }
    // stage wk tile: 32 rows x 32 f4, coalesced global, swizzled LDS col
    {
        const float4* g = (const float4*)wk;
#pragma unroll
        for (int k = 0; k < 4; ++k) {
            int g4 = t + k * 256;
            int r = g4 >> 5, c = g4 & 31;
            wk_lds[r][c ^ (r >> 3)] = g[((size_t)(b * TV + v0 + r)) * 32 + c];
        }
    }
    __syncthreads();

    const int qi = t >> 5;        // 0..7
    const int vi = t & 31;        // 0..31
    const int c3 = vi >> 3;       // swizzle key

    float a0 = 0.f, a1 = 0.f, a2 = 0.f, a3 = 0.f;
#pragma unroll 8
    for (int uu = 0; uu < 32; ++uu) {
        float4 wqv = wq_lds[qi][uu];          // 2 addrs/wave -> broadcast
        float4 wkv = wk_lds[vi][uu ^ c3];     // swizzled, conflict-reduced
        float4 sv  = sc_lds[uu];              // full broadcast
        a0 += sv.x * fast_tanh(wqv.x + wkv.x);
        a1 += sv.y * fast_tanh(wqv.y + wkv.y);
        a2 += sv.z * fast_tanh(wqv.z + wkv.z);
        a3 += sv.w * fast_tanh(wqv.w + wkv.w);
    }
    float acc = (a0 + a1) + (a2 + a3);

    const int v = v0 + vi;
    scores[((size_t)(b * TQ + q0 + qi)) * TV + v] =
        mask[v * BB + b] ? acc : NEG_INF;
}

// Softmax + context for 2 q-rows per block. Grid: B*TQ/2 = 512 blocks.
__global__ __launch_bounds__(256) void softmax_ctx_kernel(
    const float* __restrict__ value,   // [TV,B,D]
    const float* __restrict__ scores,  // [B,TQ,TV]
    float* __restrict__ out)           // [TQ,B,D]
{
    const int bqp = blockIdx.x;
    const int b   = bqp >> 7;           // TQ/2 = 128 q-pairs per b
    const int q0  = (bqp & 127) * 2;
    const int t    = threadIdx.x;
    const int lane = t & 63;
    const int wid  = t >> 6;

    __shared__ float p_lds[2][TV];
    __shared__ float red[8];
    __shared__ float part[2][DD];

    // each thread owns f4 chunk t of both rows
    const float4* s0 = (const float4*)(scores + ((size_t)(b * TQ + q0)) * TV);
    const float4* s1 = (const float4*)(scores + ((size_t)(b * TQ + q0 + 1)) * TV);
    float4 x0 = s0[t], x1 = s1[t];

    // ---- row max ----
    float m0 = fmaxf(fmaxf(x0.x, x0.y), fmaxf(x0.z, x0.w));
    float m1 = fmaxf(fmaxf(x1.x, x1.y), fmaxf(x1.z, x1.w));
#pragma unroll
    for (int off = 32; off > 0; off >>= 1) {
        m0 = fmaxf(m0, __shfl_xor(m0, off, 64));
        m1 = fmaxf(m1, __shfl_xor(m1, off, 64));
    }
    if (lane == 0) { red[wid] = m0; red[4 + wid] = m1; }
    __syncthreads();
    m0 = fmaxf(fmaxf(red[0], red[1]), fmaxf(red[2], red[3]));
    m1 = fmaxf(fmaxf(red[4], red[5]), fmaxf(red[6], red[7]));

    // ---- exp + row sum ----
    float4 p0, p1;
    p0.x = __expf(x0.x - m0); p0.y = __expf(x0.y - m0);
    p0.z = __expf(x0.z - m0); p0.w = __expf(x0.w - m0);
    p1.x = __expf(x1.x - m1); p1.y = __expf(x1.y - m1);
    p1.z = __expf(x1.z - m1); p1.w = __expf(x1.w - m1);
    float s0sum = (p0.x + p0.y) + (p0.z + p0.w);
    float s1sum = (p1.x + p1.y) + (p1.z + p1.w);
#pragma unroll
    for (int off = 32; off > 0; off >>= 1) {
        s0sum += __shfl_xor(s0sum, off, 64);
        s1sum += __shfl_xor(s1sum, off, 64);
    }
    __syncthreads();   // everyone done reading red (max) before overwrite
    if (lane == 0) { red[wid] = s0sum; red[4 + wid] = s1sum; }
    __syncthreads();
    float inv0 = 1.f / (red[0] + red[1] + red[2] + red[3]);
    float inv1 = 1.f / (red[4] + red[5] + red[6] + red[7]);

    ((float4*)&p_lds[0][0])[t] =
        make_float4(p0.x * inv0, p0.y * inv0, p0.z * inv0, p0.w * inv0);
    ((float4*)&p_lds[1][0])[t] =
        make_float4(p1.x * inv1, p1.y * inv1, p1.z * inv1, p1.w * inv1);
    __syncthreads();

    // ---- context: half-split over v, both q accumulated per thread ----
    const int d    = t & 127;
    const int half = t >> 7;               // v in [half*512, half*512+512)
    const int vbase = half * 512;
    const float* vp  = value + (size_t)vbase * BB * DD + b * DD + d;
    const float* pl0 = &p_lds[0][vbase];
    const float* pl1 = &p_lds[1][vbase];

    float acc0 = 0.f, acc1 = 0.f;
#pragma unroll 8
    for (int i = 0; i < 512; ++i) {
        float vv = vp[(size_t)i * BB * DD];   // coalesced over d
        acc0 += pl0[i] * vv;                  // p_lds broadcast
        acc1 += pl1[i] * vv;
    }

    if (half == 1) { part[0][d] = acc0; part[1][d] = acc1; }
    __syncthreads();
    if (half == 0) {
        out[((size_t)(q0 + 0) * BB + b) * DD + d] = acc0 + part[0][d];
        out[((size_t)(q0 + 1) * BB + b) * DD + d] = acc1 + part[1][d];
    }
}

extern "C" void kernel_launch(void* const* d_in, const int* in_sizes, int n_in,
                              void* d_out, int out_size, void* d_ws, size_t ws_size,
                              hipStream_t stream) {
    const float* query = (const float*)d_in[0];  // [TQ,B,D]
    const float* value = (const float*)d_in[1];  // [TV,B,D]
    const int*   mask  = (const int*)  d_in[2];  // [TV,B]
    const float* W1    = (const float*)d_in[3];  // [D,U]
    const float* W2    = (const float*)d_in[4];  // [D,U]
    const float* scale = (const float*)d_in[5];  // [U]
    float* out = (float*)d_out;

    float* wq     = (float*)d_ws;                    // [B,TQ,U]  512 KB
    float* wk     = wq + (size_t)BB * TQ * UU;       // [B,TV,U]  2 MB
    float* scores = wk + (size_t)BB * TV * UU;       // [B,TQ,TV] 4 MB

    proj_kernel<<<TQ * BB, 128, 0, stream>>>(query, W1, wq, TQ);
    proj_kernel<<<TV * BB, 128, 0, stream>>>(value, W2, wk, TV);
    scores_kernel<<<dim3(TV / 32, TQ / 8, BB), 256, 0, stream>>>(
        wq, wk, scale, mask, scores);
    softmax_ctx_kernel<<<BB * TQ / 2, 256, 0, stream>>>(value, scores, out);
}

// Round 4
// 70.554 us; speedup vs baseline: 3.0470x; 1.0669x over previous
//
#include <hip/hip_runtime.h>

// Bahdanau additive attention, fp32.
// query [TQ,B,D], value [TV,B,D], mask [TV,B] (int32), W1 [D,U], W2 [D,U], scale [U]
// out [TQ,B,D]

#define TQ 256
#define TV 1024
#define BB 4
#define DD 128
#define UU 128
#define NEG_INF -1e9f
#define C2LOG2E 2.8853900817779268f   // 2*log2(e): exp2(C*(wq+wk)) = exp(2*(wq+wk))

// ---------------- prep: svm2 = -2*scale, S = sum(scale) ----------------
__global__ __launch_bounds__(128) void prep_kernel(
    const float* __restrict__ scale, float* __restrict__ svm2,
    float* __restrict__ Ssum)
{
    const int t = threadIdx.x;
    float s = scale[t];
    svm2[t] = -2.f * s;
    float x = s;
#pragma unroll
    for (int off = 32; off > 0; off >>= 1) x += __shfl_xor(x, off, 64);
    __shared__ float r2[2];
    if ((t & 63) == 0) r2[t >> 6] = x;
    __syncthreads();
    if (t == 0) Ssum[0] = r2[0] + r2[1];
}

// ---------------- proj: out[b][t][u] = C * (X[t][b][:] @ W[:,u]) ----------------
// W staged in LDS once per block; 8 rows (flat t*B+b) per block, 256 threads.
__global__ __launch_bounds__(256) void proj_kernel(
    const float* __restrict__ X, const float* __restrict__ W,
    float* __restrict__ out, int T)
{
    __shared__ float Wl[DD * UU];     // 64 KB
    __shared__ float xs[8][DD];       // 4 KB
    const int t = threadIdx.x;
    const int R0 = blockIdx.x * 8;    // flat row index = tt*BB + b

    {   // stage W (flat copy, identical layout)
        const float4* Wg = (const float4*)W;
        float4* Wl4 = (float4*)Wl;
#pragma unroll
        for (int k = 0; k < 16; ++k)              // 4096 f4 / 256 thr
            Wl4[k * 256 + t] = Wg[k * 256 + t];
        // stage 8 rows of X (contiguous: X flat row rf = t*B+b)
        ((float4*)xs)[t] = ((const float4*)(X + (size_t)R0 * DD))[t];
    }
    __syncthreads();

    const int half = t >> 7;          // 0..1 -> rows half*4..half*4+3
    const int u = t & 127;
    float a[4] = {0.f, 0.f, 0.f, 0.f};
#pragma unroll 4
    for (int d = 0; d < DD; ++d) {
        float wv = Wl[d * UU + u];    // 64 consecutive lanes -> conflict-free
#pragma unroll
        for (int i = 0; i < 4; ++i)
            a[i] += xs[half * 4 + i][d] * wv;   // broadcast
    }
#pragma unroll
    for (int i = 0; i < 4; ++i) {
        int rf = R0 + half * 4 + i;
        int b = rf & (BB - 1), tt = rf >> 2;
        out[((size_t)b * T + tt) * UU + u] = a[i] * C2LOG2E;
    }
}

// ---------------- scores: 16q x 64v tile, thread = 2q x 2v ----------------
// score[b,q,v] = S + sum_u svm2[u] * rcp(1 + exp2(wq'[q,u] + wk'[v,u]))
__device__ __forceinline__ float rterm(float x) {
    float e = __builtin_amdgcn_exp2f(x);
    return __builtin_amdgcn_rcpf(e + 1.f);
}

__global__ __launch_bounds__(256) void scores_kernel(
    const float* __restrict__ wq,     // [B,TQ,U] prescaled by C
    const float* __restrict__ wk,     // [B,TV,U] prescaled by C
    const float* __restrict__ svm2,   // [U]  (-2*scale)
    const float* __restrict__ Ssum,   // [1]
    float* __restrict__ scores)       // [B,TQ,TV] raw (mask applied later)
{
    const int b  = blockIdx.z;
    const int q0 = blockIdx.y * 16;
    const int v0 = blockIdx.x * 64;
    const int t  = threadIdx.x;

    __shared__ float4 wq_lds[16 * 32];   // 8 KB, linear
    __shared__ float4 wk_lds[64 * 32];   // 32 KB, col ^ (row&7) swizzle
    // total LDS = 40 KB exactly -> 4 blocks/CU, grid = 4 blocks/CU

    {
        const float4* g = (const float4*)wq + ((size_t)(b * TQ + q0)) * 32;
#pragma unroll
        for (int k = 0; k < 2; ++k) {
            int i = k * 256 + t;
            wq_lds[i] = g[i];
        }
    }
    {
        const float4* g = (const float4*)wk + ((size_t)(b * TV + v0)) * 32;
#pragma unroll
        for (int k = 0; k < 8; ++k) {
            int i = k * 256 + t;
            int r = i >> 5, c = i & 31;
            wk_lds[r * 32 + (c ^ (r & 7))] = g[i];
        }
    }
    __syncthreads();

    const int qp = t >> 5;            // 0..7  -> q rows {2qp, 2qp+1}
    const int vp = t & 31;            // 0..31 -> v cols {vp, vp+32}
    const int sx = vp & 7;            // same for vp+32
    const float4* Ar0 = wq_lds + (2 * qp) * 32;
    const float4* Ar1 = Ar0 + 32;
    const float4* Kr0 = wk_lds + vp * 32;
    const float4* Kr1 = wk_lds + (vp + 32) * 32;
    const float4* sv4 = (const float4*)svm2;   // uniform -> s_load

    float s00 = 0.f, s01 = 0.f, s10 = 0.f, s11 = 0.f;
#pragma unroll 8
    for (int uu = 0; uu < 32; ++uu) {
        float4 A0 = Ar0[uu];          // broadcast (2 addrs/wave)
        float4 A1 = Ar1[uu];
        int cs = uu ^ sx;
        float4 K0 = Kr0[cs];          // column read, swizzled
        float4 K1 = Kr1[cs];
        float4 sv = sv4[uu];          // scalar
        s00 += sv.x * rterm(A0.x + K0.x);
        s00 += sv.y * rterm(A0.y + K0.y);
        s00 += sv.z * rterm(A0.z + K0.z);
        s00 += sv.w * rterm(A0.w + K0.w);
        s01 += sv.x * rterm(A0.x + K1.x);
        s01 += sv.y * rterm(A0.y + K1.y);
        s01 += sv.z * rterm(A0.z + K1.z);
        s01 += sv.w * rterm(A0.w + K1.w);
        s10 += sv.x * rterm(A1.x + K0.x);
        s10 += sv.y * rterm(A1.y + K0.y);
        s10 += sv.z * rterm(A1.z + K0.z);
        s10 += sv.w * rterm(A1.w + K0.w);
        s11 += sv.x * rterm(A1.x + K1.x);
        s11 += sv.y * rterm(A1.y + K1.y);
        s11 += sv.z * rterm(A1.z + K1.z);
        s11 += sv.w * rterm(A1.w + K1.w);
    }
    const float S = Ssum[0];
    float* row0 = scores + ((size_t)(b * TQ + q0 + 2 * qp)) * TV + v0;
    float* row1 = row0 + TV;
    row0[vp]      = S + s00;
    row0[vp + 32] = S + s01;
    row1[vp]      = S + s10;
    row1[vp + 32] = S + s11;
}

// ---------------- softmax + context: 4 q rows per block ----------------
__global__ __launch_bounds__(256) void softmax_ctx_kernel(
    const float* __restrict__ value,   // [TV,B,D]
    const int*   __restrict__ mask,    // [TV,B]
    const float* __restrict__ scores,  // [B,TQ,TV]
    float* __restrict__ out)           // [TQ,B,D]
{
    const int bi = blockIdx.x;
    const int b  = bi >> 6;             // 64 q-quads per batch
    const int q0 = (bi & 63) * 4;
    const int t = threadIdx.x, lane = t & 63, wid = t >> 6;

    __shared__ float p_lds[4][TV];      // 16 KB
    __shared__ float red[4][4];
    __shared__ float part[4][DD];       // 2 KB

    // this thread's f4 chunk (v = 4t..4t+3) of all 4 rows, masked
    int mv[4];
#pragma unroll
    for (int k = 0; k < 4; ++k) mv[k] = mask[(4 * t + k) * BB + b];

    float4 x[4];
    const float* srow = scores + ((size_t)(b * TQ + q0)) * TV;
#pragma unroll
    for (int j = 0; j < 4; ++j) {
        float4 xv = ((const float4*)(srow + (size_t)j * TV))[t];
        xv.x = mv[0] ? xv.x : NEG_INF;
        xv.y = mv[1] ? xv.y : NEG_INF;
        xv.z = mv[2] ? xv.z : NEG_INF;
        xv.w = mv[3] ? xv.w : NEG_INF;
        x[j] = xv;
    }

    // ---- per-row max ----
    float m[4];
#pragma unroll
    for (int j = 0; j < 4; ++j) {
        float mm = fmaxf(fmaxf(x[j].x, x[j].y), fmaxf(x[j].z, x[j].w));
#pragma unroll
        for (int off = 32; off > 0; off >>= 1)
            mm = fmaxf(mm, __shfl_xor(mm, off, 64));
        if (lane == 0) red[j][wid] = mm;
        m[j] = mm;
    }
    __syncthreads();
#pragma unroll
    for (int j = 0; j < 4; ++j)
        m[j] = fmaxf(fmaxf(red[j][0], red[j][1]), fmaxf(red[j][2], red[j][3]));
    __syncthreads();   // done reading red before sum phase overwrites

    // ---- exp (unnormalized) + row sums ----
    float inv[4];
#pragma unroll
    for (int j = 0; j < 4; ++j) {
        float4 p;
        p.x = __expf(x[j].x - m[j]);
        p.y = __expf(x[j].y - m[j]);
        p.z = __expf(x[j].z - m[j]);
        p.w = __expf(x[j].w - m[j]);
        ((float4*)&p_lds[j][0])[t] = p;
        float ss = (p.x + p.y) + (p.z + p.w);
#pragma unroll
        for (int off = 32; off > 0; off >>= 1)
            ss += __shfl_xor(ss, off, 64);
        if (lane == 0) red[j][wid] = ss;
    }
    __syncthreads();
#pragma unroll
    for (int j = 0; j < 4; ++j)
        inv[j] = 1.f / (red[j][0] + red[j][1] + red[j][2] + red[j][3]);

    // ---- context: half-split over v ----
    const int d = t & 127;
    const int half = t >> 7;
    const int vbase = half * 512;
    const float* vptr = value + ((size_t)vbase * BB + b) * DD + d;
    float acc[4] = {0.f, 0.f, 0.f, 0.f};
#pragma unroll 8
    for (int i = 0; i < 512; ++i) {
        float vv = vptr[(size_t)i * BB * DD];   // coalesced over d
#pragma unroll
        for (int j = 0; j < 4; ++j)
            acc[j] += p_lds[j][vbase + i] * vv; // broadcast
    }
    if (half) {
#pragma unroll
        for (int j = 0; j < 4; ++j) part[j][d] = acc[j];
    }
    __syncthreads();
    if (!half) {
#pragma unroll
        for (int j = 0; j < 4; ++j)
            out[((size_t)(q0 + j) * BB + b) * DD + d] =
                (acc[j] + part[j][d]) * inv[j];
    }
}

extern "C" void kernel_launch(void* const* d_in, const int* in_sizes, int n_in,
                              void* d_out, int out_size, void* d_ws, size_t ws_size,
                              hipStream_t stream) {
    const float* query = (const float*)d_in[0];  // [TQ,B,D]
    const float* value = (const float*)d_in[1];  // [TV,B,D]
    const int*   mask  = (const int*)  d_in[2];  // [TV,B]
    const float* W1    = (const float*)d_in[3];  // [D,U]
    const float* W2    = (const float*)d_in[4];  // [D,U]
    const float* scale = (const float*)d_in[5];  // [U]
    float* out = (float*)d_out;

    float* wq     = (float*)d_ws;                    // [B,TQ,U]
    float* wk     = wq + (size_t)BB * TQ * UU;       // [B,TV,U]
    float* scores = wk + (size_t)BB * TV * UU;       // [B,TQ,TV]
    float* svm2   = scores + (size_t)BB * TQ * TV;   // [U]
    float* Ssum   = svm2 + UU;                       // [1]

    prep_kernel<<<1, 128, 0, stream>>>(scale, svm2, Ssum);
    proj_kernel<<<TQ * BB / 8, 256, 0, stream>>>(query, W1, wq, TQ);
    proj_kernel<<<TV * BB / 8, 256, 0, stream>>>(value, W2, wk, TV);
    scores_kernel<<<dim3(TV / 64, TQ / 16, BB), 256, 0, stream>>>(
        wq, wk, svm2, Ssum, scores);
    softmax_ctx_kernel<<<BB * TQ / 4, 256, 0, stream>>>(value, mask, scores, out);
}

// Round 5
// 65.871 us; speedup vs baseline: 3.2636x; 1.0711x over previous
//
#include <hip/hip_runtime.h>

// Bahdanau additive attention, fp32, mask-compacted.
// query [TQ,B,D], value [TV,B,D], mask [TV,B] (int32), W1 [D,U], W2 [D,U], scale [U]
// out [TQ,B,D]

#define TQ 256
#define TV 1024
#define BB 4
#define DD 128
#define UU 128
#define NEG_INF -1e9f
#define C2LOG2E 2.8853900817779268f   // 2*log2(e): exp2(C*(wq+wk)) = exp(2*(wq+wk))

// ---------- compact: per-b ordered list of valid v indices + count ----------
__global__ __launch_bounds__(256) void compact_kernel(
    const int* __restrict__ mask,    // [TV,B]
    int* __restrict__ valid_idx,     // [B,TV]
    int* __restrict__ nvalid)        // [B]
{
    const int b = blockIdx.x;
    const int t = threadIdx.x, lane = t & 63, wid = t >> 6;
    __shared__ int wsum[4];

    int m[4];
#pragma unroll
    for (int k = 0; k < 4; ++k) m[k] = mask[(4 * t + k) * BB + b] ? 1 : 0;
    int cnt = m[0] + m[1] + m[2] + m[3];

    // wave inclusive scan
    int pre = cnt;
#pragma unroll
    for (int off = 1; off < 64; off <<= 1) {
        int y = __shfl_up(pre, off, 64);
        if (lane >= off) pre += y;
    }
    if (lane == 63) wsum[wid] = pre;
    __syncthreads();
    int base = 0;
#pragma unroll
    for (int w = 0; w < 4; ++w) if (w < wid) base += wsum[w];
    int total = wsum[0] + wsum[1] + wsum[2] + wsum[3];
    int idx = base + pre - cnt;     // exclusive position

#pragma unroll
    for (int k = 0; k < 4; ++k)
        if (m[k]) valid_idx[b * TV + (idx++)] = 4 * t + k;
    // pad tail with 0 (a guaranteed-valid row) so gathers stay in-bounds
    for (int i = t; i < TV; i += 256)
        if (i >= total) valid_idx[b * TV + i] = 0;
    if (t == 0) nvalid[b] = total;
}

// ---------- proj (q and v in one launch): out = C * (X @ W) ----------
__global__ __launch_bounds__(256) void proj_all_kernel(
    const float* __restrict__ query, const float* __restrict__ value,
    const float* __restrict__ W1, const float* __restrict__ W2,
    float* __restrict__ wq, float* __restrict__ wk)
{
    __shared__ float Wl[DD * UU];     // 64 KB
    __shared__ float xs[8][DD];       // 4 KB
    const int t = threadIdx.x;

    const bool isq = blockIdx.x < (TQ * BB / 8);
    const float* X = isq ? query : value;
    const float* W = isq ? W1 : W2;
    float* out     = isq ? wq : wk;
    const int T    = isq ? TQ : TV;
    const int R0   = (isq ? blockIdx.x : blockIdx.x - TQ * BB / 8) * 8;

    {
        const float4* Wg = (const float4*)W;
        float4* Wl4 = (float4*)Wl;
#pragma unroll
        for (int k = 0; k < 16; ++k)
            Wl4[k * 256 + t] = Wg[k * 256 + t];
        ((float4*)xs)[t] = ((const float4*)(X + (size_t)R0 * DD))[t];
    }
    __syncthreads();

    const int half = t >> 7;
    const int u = t & 127;
    float a[4] = {0.f, 0.f, 0.f, 0.f};
#pragma unroll 4
    for (int d = 0; d < DD; ++d) {
        float wv = Wl[d * UU + u];
#pragma unroll
        for (int i = 0; i < 4; ++i)
            a[i] += xs[half * 4 + i][d] * wv;
    }
#pragma unroll
    for (int i = 0; i < 4; ++i) {
        int rf = R0 + half * 4 + i;
        int b = rf & (BB - 1), tt = rf >> 2;
        out[((size_t)b * T + tt) * UU + u] = a[i] * C2LOG2E;
    }
}

// ---------- scores over compact v domain ----------
// score[b,q,i] = S + sum_u svm2[u] * rcp(1 + exp2(wq'[q,u] + wk'[vidx[i],u]))
__device__ __forceinline__ float rterm(float x) {
    float e = __builtin_amdgcn_exp2f(x);
    return __builtin_amdgcn_rcpf(e + 1.f);
}

__global__ __launch_bounds__(256) void scores_kernel(
    const float* __restrict__ wq,      // [B,TQ,U] prescaled by C
    const float* __restrict__ wk,      // [B,TV,U] prescaled by C
    const float* __restrict__ scale,   // [U]
    const int*   __restrict__ valid_idx, // [B,TV]
    const int*   __restrict__ nvalid,    // [B]
    float* __restrict__ scores)        // [B,TQ,TV] compact-indexed
{
    const int b  = blockIdx.z;
    const int nv = nvalid[b];
    const int v0 = blockIdx.x * 32;
    if (v0 >= nv) return;               // uniform early-exit for padding tiles
    const int q0 = blockIdx.y * 16;
    const int t  = threadIdx.x;
    const int lane = t & 63, wid = t >> 6;

    __shared__ float4 wq_lds[16 * 32];   // 8 KB
    __shared__ float4 wk_lds[32 * 32];   // 16 KB, col ^ (row&7) swizzle
    __shared__ float  sc_lds[UU];        // -2*scale
    __shared__ int    vidx[32];
    __shared__ float  wred[4];

    // scale staging + block sum S
    float sv = (t < UU) ? scale[t] : 0.f;
    if (t < UU) sc_lds[t] = -2.f * sv;
    float ssum = sv;
#pragma unroll
    for (int off = 32; off > 0; off >>= 1) ssum += __shfl_xor(ssum, off, 64);
    if (lane == 0) wred[wid] = ssum;
    if (t < 32) vidx[t] = valid_idx[b * TV + v0 + t];
    {
        const float4* g = (const float4*)wq + ((size_t)(b * TQ + q0)) * 32;
#pragma unroll
        for (int k = 0; k < 2; ++k) {
            int i = k * 256 + t;
            wq_lds[i] = g[i];
        }
    }
    __syncthreads();
    const float S = wred[0] + wred[1] + wred[2] + wred[3];
    {
        const float4* g = (const float4*)wk;
#pragma unroll
        for (int k = 0; k < 4; ++k) {
            int i = k * 256 + t;
            int r = i >> 5, c = i & 31;
            wk_lds[r * 32 + (c ^ (r & 7))] =
                g[((size_t)(b * TV + vidx[r])) * 32 + c];
        }
    }
    __syncthreads();

    const int qp = t >> 5;            // 0..7 -> q rows {2qp, 2qp+1}
    const int vi = t & 31;            // compact col
    const int sx = vi & 7;
    const float4* Ar0 = wq_lds + (2 * qp) * 32;
    const float4* Ar1 = Ar0 + 32;
    const float4* Kr  = wk_lds + vi * 32;
    const float4* sv4 = (const float4*)sc_lds;

    float s0 = 0.f, s1 = 0.f;
#pragma unroll 8
    for (int uu = 0; uu < 32; ++uu) {
        float4 A0 = Ar0[uu];
        float4 A1 = Ar1[uu];
        float4 K  = Kr[uu ^ sx];
        float4 s  = sv4[uu];
        s0 += s.x * rterm(A0.x + K.x);
        s0 += s.y * rterm(A0.y + K.y);
        s0 += s.z * rterm(A0.z + K.z);
        s0 += s.w * rterm(A0.w + K.w);
        s1 += s.x * rterm(A1.x + K.x);
        s1 += s.y * rterm(A1.y + K.y);
        s1 += s.z * rterm(A1.z + K.z);
        s1 += s.w * rterm(A1.w + K.w);
    }
    float* row0 = scores + ((size_t)(b * TQ + q0 + 2 * qp)) * TV + v0;
    row0[vi]      = S + s0;
    row0[TV + vi] = S + s1;
}

// ---------- softmax + context over compact domain, 4 q rows / block ----------
__global__ __launch_bounds__(256) void softmax_ctx_kernel(
    const float* __restrict__ value,     // [TV,B,D]
    const int*   __restrict__ valid_idx, // [B,TV]
    const int*   __restrict__ nvalid,    // [B]
    const float* __restrict__ scores,    // [B,TQ,TV] compact
    float* __restrict__ out)             // [TQ,B,D]
{
    const int bi = blockIdx.x;
    const int b  = bi >> 6;
    const int q0 = (bi & 63) * 4;
    const int nv = nvalid[b];
    const int t = threadIdx.x, lane = t & 63, wid = t >> 6;

    __shared__ float p_lds[4][TV];      // 16 KB
    __shared__ int   vidx[TV];          // 4 KB
    __shared__ float red[4][4];
    __shared__ float part[4][DD];       // 2 KB

    ((int4*)vidx)[t] = ((const int4*)(valid_idx + b * TV))[t];

    float4 x[4];
    const float* srow = scores + ((size_t)(b * TQ + q0)) * TV;
#pragma unroll
    for (int j = 0; j < 4; ++j) {
        float4 xv = ((const float4*)(srow + (size_t)j * TV))[t];
        int e = 4 * t;
        xv.x = (e + 0 < nv) ? xv.x : NEG_INF;
        xv.y = (e + 1 < nv) ? xv.y : NEG_INF;
        xv.z = (e + 2 < nv) ? xv.z : NEG_INF;
        xv.w = (e + 3 < nv) ? xv.w : NEG_INF;
        x[j] = xv;
    }

    // per-row max
    float m[4];
#pragma unroll
    for (int j = 0; j < 4; ++j) {
        float mm = fmaxf(fmaxf(x[j].x, x[j].y), fmaxf(x[j].z, x[j].w));
#pragma unroll
        for (int off = 32; off > 0; off >>= 1)
            mm = fmaxf(mm, __shfl_xor(mm, off, 64));
        if (lane == 0) red[j][wid] = mm;
        m[j] = mm;
    }
    __syncthreads();
#pragma unroll
    for (int j = 0; j < 4; ++j)
        m[j] = fmaxf(fmaxf(red[j][0], red[j][1]), fmaxf(red[j][2], red[j][3]));
    __syncthreads();

    // exp (unnormalized) + sums
    float inv[4];
#pragma unroll
    for (int j = 0; j < 4; ++j) {
        float4 p;
        p.x = __expf(x[j].x - m[j]);
        p.y = __expf(x[j].y - m[j]);
        p.z = __expf(x[j].z - m[j]);
        p.w = __expf(x[j].w - m[j]);
        ((float4*)&p_lds[j][0])[t] = p;
        float ss = (p.x + p.y) + (p.z + p.w);
#pragma unroll
        for (int off = 32; off > 0; off >>= 1)
            ss += __shfl_xor(ss, off, 64);
        if (lane == 0) red[j][wid] = ss;
    }
    __syncthreads();
#pragma unroll
    for (int j = 0; j < 4; ++j)
        inv[j] = 1.f / (red[j][0] + red[j][1] + red[j][2] + red[j][3]);

    // context: gather valid value rows, odd/even i split across halves
    const int d = t & 127;
    const int half = t >> 7;
    float acc[4] = {0.f, 0.f, 0.f, 0.f};
    const float* vbase = value + b * DD + d;
#pragma unroll 4
    for (int i = half; i < nv; i += 2) {
        float vv = vbase[(size_t)vidx[i] * BB * DD];
#pragma unroll
        for (int j = 0; j < 4; ++j)
            acc[j] += p_lds[j][i] * vv;
    }
    if (half) {
#pragma unroll
        for (int j = 0; j < 4; ++j) part[j][d] = acc[j];
    }
    __syncthreads();
    if (!half) {
#pragma unroll
        for (int j = 0; j < 4; ++j)
            out[((size_t)(q0 + j) * BB + b) * DD + d] =
                (acc[j] + part[j][d]) * inv[j];
    }
}

extern "C" void kernel_launch(void* const* d_in, const int* in_sizes, int n_in,
                              void* d_out, int out_size, void* d_ws, size_t ws_size,
                              hipStream_t stream) {
    const float* query = (const float*)d_in[0];  // [TQ,B,D]
    const float* value = (const float*)d_in[1];  // [TV,B,D]
    const int*   mask  = (const int*)  d_in[2];  // [TV,B]
    const float* W1    = (const float*)d_in[3];  // [D,U]
    const float* W2    = (const float*)d_in[4];  // [D,U]
    const float* scale = (const float*)d_in[5];  // [U]
    float* out = (float*)d_out;

    float* wq      = (float*)d_ws;                    // [B,TQ,U]
    float* wk      = wq + (size_t)BB * TQ * UU;       // [B,TV,U]
    float* scores  = wk + (size_t)BB * TV * UU;       // [B,TQ,TV]
    int*   vidx    = (int*)(scores + (size_t)BB * TQ * TV); // [B,TV]
    int*   nvalid  = vidx + BB * TV;                  // [B]

    compact_kernel<<<BB, 256, 0, stream>>>(mask, vidx, nvalid);
    proj_all_kernel<<<(TQ * BB + TV * BB) / 8, 256, 0, stream>>>(
        query, value, W1, W2, wq, wk);
    scores_kernel<<<dim3(TV / 32, TQ / 16, BB), 256, 0, stream>>>(
        wq, wk, scale, vidx, nvalid, scores);
    softmax_ctx_kernel<<<BB * TQ / 4, 256, 0, stream>>>(
        value, vidx, nvalid, scores, out);
}

// Round 6
// 48.588 us; speedup vs baseline: 4.4246x; 1.3557x over previous
//
#include <hip/hip_runtime.h>

// Bahdanau additive attention, fp32, mask-compacted, exp-factored scores.
// score[b,q,v] = S - 2*sum_u s_u / (1 + Eq[q,u]*Ek[v,u]),  E* = exp(2*proj)
// query [TQ,B,D], value [TV,B,D], mask [TV,B] (int32), W1 [D,U], W2 [D,U], scale [U]

#define TQ 256
#define TV 1024
#define BB 4
#define DD 128
#define UU 128
#define NEG_INF -1e9f
#define C2LOG2E 2.8853900817779268f   // 2*log2(e)

// ---------- compact: per-b valid v list + count; block 0 also computes S ----------
__global__ __launch_bounds__(256) void compact_kernel(
    const int* __restrict__ mask,    // [TV,B]
    const float* __restrict__ scale, // [U]
    int* __restrict__ valid_idx,     // [B,TV]
    int* __restrict__ nvalid,        // [B]
    float* __restrict__ Ssum)        // [1]
{
    const int b = blockIdx.x;
    const int t = threadIdx.x, lane = t & 63, wid = t >> 6;
    __shared__ int wsum[4];
    __shared__ float sred[2];

    int m[4];
#pragma unroll
    for (int k = 0; k < 4; ++k) m[k] = mask[(4 * t + k) * BB + b] ? 1 : 0;
    int cnt = m[0] + m[1] + m[2] + m[3];

    // wave inclusive scan
    int pre = cnt;
#pragma unroll
    for (int off = 1; off < 64; off <<= 1) {
        int y = __shfl_up(pre, off, 64);
        if (lane >= off) pre += y;
    }
    if (lane == 63) wsum[wid] = pre;

    // S = sum(scale) (waves 0-1)
    float sv_ = (t < UU) ? scale[t] : 0.f;
#pragma unroll
    for (int off = 32; off > 0; off >>= 1) sv_ += __shfl_xor(sv_, off, 64);
    if (t == 0)  sred[0] = sv_;
    if (t == 64) sred[1] = sv_;
    __syncthreads();

    int base = 0;
#pragma unroll
    for (int w = 0; w < 4; ++w) if (w < wid) base += wsum[w];
    int total = wsum[0] + wsum[1] + wsum[2] + wsum[3];
    int idx = base + pre - cnt;

#pragma unroll
    for (int k = 0; k < 4; ++k)
        if (m[k]) valid_idx[b * TV + (idx++)] = 4 * t + k;
    for (int i = t; i < TV; i += 256)
        if (i >= total) valid_idx[b * TV + i] = 0;
    if (t == 0) nvalid[b] = total;
    if (b == 0 && t == 0) Ssum[0] = sred[0] + sred[1];
}

// ---------- proj (q and v in one launch): E = exp2(C * (X @ W)) ----------
__global__ __launch_bounds__(256) void proj_all_kernel(
    const float* __restrict__ query, const float* __restrict__ value,
    const float* __restrict__ W1, const float* __restrict__ W2,
    float* __restrict__ Eq, float* __restrict__ Ek)
{
    __shared__ float Wl[DD * UU];     // 64 KB
    __shared__ float xs[8][DD];
    const int t = threadIdx.x;

    const bool isq = blockIdx.x < (TQ * BB / 8);
    const float* X = isq ? query : value;
    const float* W = isq ? W1 : W2;
    float* out     = isq ? Eq : Ek;
    const int T    = isq ? TQ : TV;
    const int R0   = (isq ? blockIdx.x : blockIdx.x - TQ * BB / 8) * 8;

    {
        const float4* Wg = (const float4*)W;
        float4* Wl4 = (float4*)Wl;
#pragma unroll
        for (int k = 0; k < 16; ++k)
            Wl4[k * 256 + t] = Wg[k * 256 + t];
        ((float4*)xs)[t] = ((const float4*)(X + (size_t)R0 * DD))[t];
    }
    __syncthreads();

    const int half = t >> 7;
    const int u = t & 127;
    float a[4] = {0.f, 0.f, 0.f, 0.f};
#pragma unroll 4
    for (int d = 0; d < DD; ++d) {
        float wv = Wl[d * UU + u];
#pragma unroll
        for (int i = 0; i < 4; ++i)
            a[i] += xs[half * 4 + i][d] * wv;
    }
#pragma unroll
    for (int i = 0; i < 4; ++i) {
        int rf = R0 + half * 4 + i;
        int b = rf & (BB - 1), tt = rf >> 2;
        out[((size_t)b * T + tt) * UU + u] =
            __builtin_amdgcn_exp2f(a[i] * C2LOG2E);   // exp(2*proj)
    }
}

// ---------- scores over compact v domain: 16q x 64v, thread = 2q x 2v ----------
__global__ __launch_bounds__(256) void scores_kernel(
    const float* __restrict__ Eq,        // [B,TQ,U]
    const float* __restrict__ Ek,        // [B,TV,U]
    const float* __restrict__ scale,     // [U]
    const float* __restrict__ Ssum,      // [1]
    const int*   __restrict__ valid_idx, // [B,TV]
    const int*   __restrict__ nvalid,    // [B]
    float* __restrict__ scores)          // [B,TQ,TV] compact-indexed
{
    const int b  = blockIdx.z;
    const int nv = nvalid[b];
    const int v0 = blockIdx.x * 64;
    if (v0 >= nv) return;
    const int q0 = blockIdx.y * 16;
    const int t  = threadIdx.x;

    __shared__ float4 eq_lds[16 * 32];   // 8 KB
    __shared__ float4 ek_lds[64 * 32];   // 32 KB, col ^ (row&7) swizzle
    __shared__ int    vidx[64];

    if (t < 64) vidx[t] = valid_idx[b * TV + v0 + t];
    {
        const float4* g = (const float4*)Eq + ((size_t)(b * TQ + q0)) * 32;
        eq_lds[t]       = g[t];
        eq_lds[256 + t] = g[256 + t];
    }
    __syncthreads();
    {
        const float4* g = (const float4*)Ek;
#pragma unroll
        for (int k = 0; k < 8; ++k) {
            int i = k * 256 + t;
            int r = i >> 5, c = i & 31;
            ek_lds[r * 32 + (c ^ (r & 7))] =
                g[((size_t)(b * TV + vidx[r])) * 32 + c];
        }
    }
    __syncthreads();

    const int qp = t >> 5;            // 0..7 -> q rows {2qp, 2qp+1}
    const int vp = t & 31;            // v cols {vp, vp+32}
    const int sx = vp & 7;
    const float4* Ar0 = eq_lds + (2 * qp) * 32;
    const float4* Ar1 = Ar0 + 32;
    const float4* Kr0 = ek_lds + vp * 32;
    const float4* Kr1 = ek_lds + (vp + 32) * 32;
    const float4* S4  = (const float4*)scale;   // uniform -> scalar loads

    float a00 = 0.f, a01 = 0.f, a10 = 0.f, a11 = 0.f;

    // pair-batched rcp: 7 VALU + 1 rcp per 2 elements
#define PAIR(Acomp, Kvec, svc, accA, accB)                           \
    {                                                                \
        float d0 = __builtin_fmaf(A0.Acomp, Kvec.Acomp, 1.f);        \
        float d1 = __builtin_fmaf(A1.Acomp, Kvec.Acomp, 1.f);        \
        float R  = __builtin_amdgcn_rcpf(d0 * d1);                   \
        accA = __builtin_fmaf(svc, R * d1, accA);                    \
        accB = __builtin_fmaf(svc, R * d0, accB);                    \
    }

#pragma unroll 8
    for (int uu = 0; uu < 32; ++uu) {
        float4 A0 = Ar0[uu];
        float4 A1 = Ar1[uu];
        int cs = uu ^ sx;
        float4 K0 = Kr0[cs];
        float4 K1 = Kr1[cs];
        float4 sv = S4[uu];
        PAIR(x, K0, sv.x, a00, a10)
        PAIR(y, K0, sv.y, a00, a10)
        PAIR(z, K0, sv.z, a00, a10)
        PAIR(w, K0, sv.w, a00, a10)
        PAIR(x, K1, sv.x, a01, a11)
        PAIR(y, K1, sv.y, a01, a11)
        PAIR(z, K1, sv.z, a01, a11)
        PAIR(w, K1, sv.w, a01, a11)
    }
#undef PAIR

    const float S = Ssum[0];
    float* row0 = scores + ((size_t)(b * TQ + q0 + 2 * qp)) * TV + v0;
    row0[vp]           = __builtin_fmaf(-2.f, a00, S);
    row0[vp + 32]      = __builtin_fmaf(-2.f, a01, S);
    row0[TV + vp]      = __builtin_fmaf(-2.f, a10, S);
    row0[TV + vp + 32] = __builtin_fmaf(-2.f, a11, S);
}

// ---------- softmax + context: 4 q rows / block, 512 threads ----------
__global__ __launch_bounds__(512) void softmax_ctx_kernel(
    const float* __restrict__ value,     // [TV,B,D]
    const int*   __restrict__ valid_idx, // [B,TV]
    const int*   __restrict__ nvalid,    // [B]
    const float* __restrict__ scores,    // [B,TQ,TV] compact
    float* __restrict__ out)             // [TQ,B,D]
{
    const int bi = blockIdx.x;
    const int b  = bi >> 6;
    const int q0 = (bi & 63) * 4;
    const int nv = nvalid[b];
    const int t = threadIdx.x, lane = t & 63;

    __shared__ float p_lds[4][TV];       // 16 KB
    __shared__ int   vidx[TV];           // 4 KB
    __shared__ float redm[4][2];
    __shared__ float reds[4][2];
    __shared__ float part[3][4][DD];     // 6 KB

    if (t < 256) ((int4*)vidx)[t] = ((const int4*)(valid_idx + b * TV))[t];

    // ---- softmax: row j = t>>7, chunk c = t&127 handles f4 at c and c+128 ----
    const int j = t >> 7;
    const int c = t & 127;
    const int wslot = (t >> 6) & 1;      // which of the row's 2 waves

    const float* srow = scores + ((size_t)(b * TQ + q0 + j)) * TV;
    float4 x0 = ((const float4*)srow)[c];
    float4 x1 = ((const float4*)srow)[c + 128];
    const int e0 = 4 * c, e1 = 512 + 4 * c;
    x0.x = (e0 + 0 < nv) ? x0.x : NEG_INF;
    x0.y = (e0 + 1 < nv) ? x0.y : NEG_INF;
    x0.z = (e0 + 2 < nv) ? x0.z : NEG_INF;
    x0.w = (e0 + 3 < nv) ? x0.w : NEG_INF;
    x1.x = (e1 + 0 < nv) ? x1.x : NEG_INF;
    x1.y = (e1 + 1 < nv) ? x1.y : NEG_INF;
    x1.z = (e1 + 2 < nv) ? x1.z : NEG_INF;
    x1.w = (e1 + 3 < nv) ? x1.w : NEG_INF;

    float mm = fmaxf(fmaxf(fmaxf(x0.x, x0.y), fmaxf(x0.z, x0.w)),
                     fmaxf(fmaxf(x1.x, x1.y), fmaxf(x1.z, x1.w)));
#pragma unroll
    for (int off = 32; off > 0; off >>= 1)
        mm = fmaxf(mm, __shfl_xor(mm, off, 64));
    if (lane == 0) redm[j][wslot] = mm;
    __syncthreads();
    mm = fmaxf(redm[j][0], redm[j][1]);

    float4 p0, p1;
    p0.x = __expf(x0.x - mm); p0.y = __expf(x0.y - mm);
    p0.z = __expf(x0.z - mm); p0.w = __expf(x0.w - mm);
    p1.x = __expf(x1.x - mm); p1.y = __expf(x1.y - mm);
    p1.z = __expf(x1.z - mm); p1.w = __expf(x1.w - mm);
    ((float4*)&p_lds[j][0])[c]       = p0;
    ((float4*)&p_lds[j][0])[c + 128] = p1;

    float ss = ((p0.x + p0.y) + (p0.z + p0.w)) +
               ((p1.x + p1.y) + (p1.z + p1.w));
#pragma unroll
    for (int off = 32; off > 0; off >>= 1)
        ss += __shfl_xor(ss, off, 64);
    if (lane == 0) reds[j][wslot] = ss;
    __syncthreads();   // p_lds, vidx, reds all visible

    // ---- context: quarter = t>>7, d = t&127; gather i = quarter, +=4 ----
    const int qtr = t >> 7;
    const int d = t & 127;
    float acc[4] = {0.f, 0.f, 0.f, 0.f};
    const float* vbase = value + b * DD + d;
#pragma unroll 8
    for (int i = qtr; i < nv; i += 4) {
        float vv = vbase[(size_t)vidx[i] * BB * DD];
#pragma unroll
        for (int jj = 0; jj < 4; ++jj)
            acc[jj] += p_lds[jj][i] * vv;
    }
    if (qtr) {
#pragma unroll
        for (int jj = 0; jj < 4; ++jj) part[qtr - 1][jj][d] = acc[jj];
    }
    __syncthreads();
    if (qtr == 0) {
#pragma unroll
        for (int jj = 0; jj < 4; ++jj) {
            float tot = acc[jj] + part[0][jj][d] + part[1][jj][d] + part[2][jj][d];
            float invj = 1.f / (reds[jj][0] + reds[jj][1]);
            out[((size_t)(q0 + jj) * BB + b) * DD + d] = tot * invj;
        }
    }
}

extern "C" void kernel_launch(void* const* d_in, const int* in_sizes, int n_in,
                              void* d_out, int out_size, void* d_ws, size_t ws_size,
                              hipStream_t stream) {
    const float* query = (const float*)d_in[0];  // [TQ,B,D]
    const float* value = (const float*)d_in[1];  // [TV,B,D]
    const int*   mask  = (const int*)  d_in[2];  // [TV,B]
    const float* W1    = (const float*)d_in[3];  // [D,U]
    const float* W2    = (const float*)d_in[4];  // [D,U]
    const float* scale = (const float*)d_in[5];  // [U]
    float* out = (float*)d_out;

    float* Eq      = (float*)d_ws;                    // [B,TQ,U]
    float* Ek      = Eq + (size_t)BB * TQ * UU;       // [B,TV,U]
    float* scores  = Ek + (size_t)BB * TV * UU;       // [B,TQ,TV]
    int*   vidx    = (int*)(scores + (size_t)BB * TQ * TV); // [B,TV]
    int*   nvalid  = vidx + BB * TV;                  // [B]
    float* Ssum    = (float*)(nvalid + BB);           // [1]

    compact_kernel<<<BB, 256, 0, stream>>>(mask, scale, vidx, nvalid, Ssum);
    proj_all_kernel<<<(TQ * BB + TV * BB) / 8, 256, 0, stream>>>(
        query, value, W1, W2, Eq, Ek);
    scores_kernel<<<dim3(TV / 64, TQ / 16, BB), 256, 0, stream>>>(
        Eq, Ek, scale, Ssum, vidx, nvalid, scores);
    softmax_ctx_kernel<<<BB * TQ / 4, 512, 0, stream>>>(
        value, vidx, nvalid, scores, out);
}

// Round 8
// 45.081 us; speedup vs baseline: 4.7687x; 1.0778x over previous
//
#include <hip/hip_runtime.h>

// Bahdanau additive attention, fp32, mask-compacted, exp-factored scores.
// score[b,q,v] = S - 2*sum_u s_u / (1 + Eq[q,u]*Ek[v,u]),  E* = exp(2*proj)
// query [TQ,B,D], value [TV,B,D], mask [TV,B] (int32), W1 [D,U], W2 [D,U], scale [U]

#define TQ 256
#define TV 1024
#define BB 4
#define DD 128
#define UU 128
#define NEG_INF -1e9f
#define C2LOG2E 2.8853900817779268f   // 2*log2(e)

// ================= A: compact (blocks 0..3) + proj (blocks 4..643) =========
union SharedA {
  struct { float Wl[DD * UU]; float xs[8][DD]; } pj;   // 68 KB
  struct { int wsum[4]; float sred[2]; } cp;
};

__global__ __launch_bounds__(256) void prep_kernel(
    const float* __restrict__ query, const float* __restrict__ value,
    const float* __restrict__ W1, const float* __restrict__ W2,
    const int* __restrict__ mask, const float* __restrict__ scale,
    float* __restrict__ Eq, float* __restrict__ Ek,
    int* __restrict__ valid_idx, int* __restrict__ nvalid,
    float* __restrict__ Ssum)
{
  __shared__ SharedA u;
  const int t = threadIdx.x, lane = t & 63, wid = t >> 6;
  const int bid = blockIdx.x;

  if (bid < BB) {           // ---- compact (verified round 6) ----
    const int b = bid;
    int m[4];
#pragma unroll
    for (int k = 0; k < 4; ++k) m[k] = mask[(4 * t + k) * BB + b] ? 1 : 0;
    int cnt = m[0] + m[1] + m[2] + m[3];
    int pre = cnt;
#pragma unroll
    for (int off = 1; off < 64; off <<= 1) {
      int y = __shfl_up(pre, off, 64);
      if (lane >= off) pre += y;
    }
    if (lane == 63) u.cp.wsum[wid] = pre;
    float sv_ = (t < UU) ? scale[t] : 0.f;
#pragma unroll
    for (int off = 32; off > 0; off >>= 1) sv_ += __shfl_xor(sv_, off, 64);
    if (t == 0)  u.cp.sred[0] = sv_;
    if (t == 64) u.cp.sred[1] = sv_;
    __syncthreads();
    int base = 0;
#pragma unroll
    for (int w = 0; w < 4; ++w) if (w < wid) base += u.cp.wsum[w];
    int total = u.cp.wsum[0] + u.cp.wsum[1] + u.cp.wsum[2] + u.cp.wsum[3];
    int idx = base + pre - cnt;
#pragma unroll
    for (int k = 0; k < 4; ++k)
      if (m[k]) valid_idx[b * TV + (idx++)] = 4 * t + k;
    for (int i = t; i < TV; i += 256)
      if (i >= total) valid_idx[b * TV + i] = 0;  // pad with valid row 0
    if (t == 0) nvalid[b] = total;
    if (b == 0 && t == 0) Ssum[0] = u.cp.sred[0] + u.cp.sred[1];
  } else {                  // ---- proj (verified round 6) ----
    const int blk = bid - BB;
    const bool isq = blk < (TQ * BB / 8);
    const float* X = isq ? query : value;
    const float* W = isq ? W1 : W2;
    float* E       = isq ? Eq : Ek;
    const int T    = isq ? TQ : TV;
    const int R0   = (isq ? blk : blk - TQ * BB / 8) * 8;

    const float4* Wg = (const float4*)W;
    float4* Wl4 = (float4*)u.pj.Wl;
#pragma unroll
    for (int k = 0; k < 16; ++k)
      Wl4[k * 256 + t] = Wg[k * 256 + t];
    ((float4*)u.pj.xs)[t] = ((const float4*)(X + (size_t)R0 * DD))[t];
    __syncthreads();

    const int half = t >> 7;
    const int uu_ = t & 127;
    float a[4] = {0.f, 0.f, 0.f, 0.f};
#pragma unroll 4
    for (int d = 0; d < DD; ++d) {
      float wv = u.pj.Wl[d * UU + uu_];
#pragma unroll
      for (int i = 0; i < 4; ++i)
        a[i] += u.pj.xs[half * 4 + i][d] * wv;
    }
#pragma unroll
    for (int i = 0; i < 4; ++i) {
      int rf = R0 + half * 4 + i;
      int b2 = rf & (BB - 1), tt = rf >> 2;
      E[((size_t)b2 * T + tt) * UU + uu_] =
          __builtin_amdgcn_exp2f(a[i] * C2LOG2E);   // exp(2*proj)
    }
  }
}

// ================= B: scores, 16q x 64v tiles, QUAD-batched rcp ============
// 4-batched reciprocal: 17 VALU + 1 rcp per 4 score terms
#define QUAD(Av, Kv, acc)                                          \
  { float d0 = __builtin_fmaf(Av.x, Kv.x, 1.f);                    \
    float d1 = __builtin_fmaf(Av.y, Kv.y, 1.f);                    \
    float d2 = __builtin_fmaf(Av.z, Kv.z, 1.f);                    \
    float d3 = __builtin_fmaf(Av.w, Kv.w, 1.f);                    \
    float m01 = d0 * d1, m23 = d2 * d3;                            \
    float R = __builtin_amdgcn_rcpf(m01 * m23);                    \
    float q01 = R * m23, q23 = R * m01;                            \
    acc = __builtin_fmaf(sv.x, q01 * d1, acc);                     \
    acc = __builtin_fmaf(sv.y, q01 * d0, acc);                     \
    acc = __builtin_fmaf(sv.z, q23 * d3, acc);                     \
    acc = __builtin_fmaf(sv.w, q23 * d2, acc); }

__global__ __launch_bounds__(256, 4) void scores_kernel(
    const float* __restrict__ Eq,        // [B,TQ,U]
    const float* __restrict__ Ek,        // [B,TV,U]
    const float* __restrict__ scale,     // [U]
    const float* __restrict__ Ssum,      // [1]
    const int*   __restrict__ valid_idx, // [B,TV]
    const int*   __restrict__ nvalid,    // [B]
    float* __restrict__ scores)          // [B,TQ,TV] compact-indexed
{
  const int b  = blockIdx.z;
  const int nv = nvalid[b];
  const int v0 = blockIdx.x * 64;
  if (v0 >= nv) return;
  const int q0 = blockIdx.y * 16;
  const int t  = threadIdx.x;

  __shared__ float4 eq_lds[16 * 32];   // 8 KB
  __shared__ float4 ek_lds[64 * 32];   // 32 KB, col ^ (row&7) swizzle
  __shared__ int    vidx[64];

  if (t < 64) vidx[t] = valid_idx[b * TV + v0 + t];
  {
    const float4* gq = (const float4*)Eq + ((size_t)(b * TQ + q0)) * 32;
    eq_lds[t]       = gq[t];
    eq_lds[256 + t] = gq[256 + t];
  }
  __syncthreads();
  {
    const float4* gk = (const float4*)Ek;
#pragma unroll
    for (int k = 0; k < 8; ++k) {
      int i = k * 256 + t;
      int r = i >> 5, c = i & 31;
      ek_lds[r * 32 + (c ^ (r & 7))] =
          gk[((size_t)(b * TV + vidx[r])) * 32 + c];
    }
  }
  __syncthreads();

  const int qp = t >> 5;             // 0..7 -> q rows {2qp, 2qp+1}
  const int vp = t & 31;             // v cols {vp, vp+32}
  const int sx = vp & 7;
  const float4* Ar0 = eq_lds + (2 * qp) * 32;
  const float4* Ar1 = Ar0 + 32;
  const float4* Kr0 = ek_lds + vp * 32;
  const float4* Kr1 = ek_lds + (vp + 32) * 32;
  const float4* S4  = (const float4*)scale;   // uniform -> scalar loads

  float a00 = 0.f, a01 = 0.f, a10 = 0.f, a11 = 0.f;
#pragma unroll 8
  for (int uu = 0; uu < 32; ++uu) {
    float4 A0 = Ar0[uu];
    float4 A1 = Ar1[uu];
    int cs = uu ^ sx;
    float4 K0 = Kr0[cs];
    float4 K1 = Kr1[cs];
    float4 sv = S4[uu];
    QUAD(A0, K0, a00)
    QUAD(A0, K1, a01)
    QUAD(A1, K0, a10)
    QUAD(A1, K1, a11)
  }
  const float S = Ssum[0];
  float* row0 = scores + ((size_t)(b * TQ + q0 + 2 * qp)) * TV + v0;
  row0[vp]           = __builtin_fmaf(-2.f, a00, S);
  row0[vp + 32]      = __builtin_fmaf(-2.f, a01, S);
  row0[TV + vp]      = __builtin_fmaf(-2.f, a10, S);
  row0[TV + vp + 32] = __builtin_fmaf(-2.f, a11, S);
}

// ================= C: softmax + context, 4 q rows / block, 512 threads =====
__global__ __launch_bounds__(512) void softmax_ctx_kernel(
    const float* __restrict__ value,     // [TV,B,D]
    const int*   __restrict__ valid_idx, // [B,TV]
    const int*   __restrict__ nvalid,    // [B]
    const float* __restrict__ scores,    // [B,TQ,TV] compact
    float* __restrict__ out)             // [TQ,B,D]
{
  const int bi = blockIdx.x;
  const int b  = bi >> 6;
  const int q0 = (bi & 63) * 4;
  const int nv = nvalid[b];
  const int t = threadIdx.x, lane = t & 63;

  __shared__ float p_lds[4][TV];       // 16 KB
  __shared__ int   vidx[TV];           // 4 KB
  __shared__ float redm[4][2];
  __shared__ float reds[4][2];
  __shared__ float part[3][4][DD];     // 6 KB

  if (t < 256) ((int4*)vidx)[t] = ((const int4*)(valid_idx + b * TV))[t];

  // ---- softmax: row j = t>>7, chunk c = t&127 handles f4 at c and c+128 ----
  const int j = t >> 7;
  const int c = t & 127;
  const int wslot = (t >> 6) & 1;

  const float* srow = scores + ((size_t)(b * TQ + q0 + j)) * TV;
  float4 x0 = ((const float4*)srow)[c];
  float4 x1 = ((const float4*)srow)[c + 128];
  const int e0 = 4 * c, e1 = 512 + 4 * c;
  x0.x = (e0 + 0 < nv) ? x0.x : NEG_INF;
  x0.y = (e0 + 1 < nv) ? x0.y : NEG_INF;
  x0.z = (e0 + 2 < nv) ? x0.z : NEG_INF;
  x0.w = (e0 + 3 < nv) ? x0.w : NEG_INF;
  x1.x = (e1 + 0 < nv) ? x1.x : NEG_INF;
  x1.y = (e1 + 1 < nv) ? x1.y : NEG_INF;
  x1.z = (e1 + 2 < nv) ? x1.z : NEG_INF;
  x1.w = (e1 + 3 < nv) ? x1.w : NEG_INF;

  float mm = fmaxf(fmaxf(fmaxf(x0.x, x0.y), fmaxf(x0.z, x0.w)),
                   fmaxf(fmaxf(x1.x, x1.y), fmaxf(x1.z, x1.w)));
#pragma unroll
  for (int off = 32; off > 0; off >>= 1)
    mm = fmaxf(mm, __shfl_xor(mm, off, 64));
  if (lane == 0) redm[j][wslot] = mm;
  __syncthreads();
  mm = fmaxf(redm[j][0], redm[j][1]);

  float4 p0, p1;
  p0.x = __expf(x0.x - mm); p0.y = __expf(x0.y - mm);
  p0.z = __expf(x0.z - mm); p0.w = __expf(x0.w - mm);
  p1.x = __expf(x1.x - mm); p1.y = __expf(x1.y - mm);
  p1.z = __expf(x1.z - mm); p1.w = __expf(x1.w - mm);
  ((float4*)&p_lds[j][0])[c]       = p0;   // masked entries -> p == 0
  ((float4*)&p_lds[j][0])[c + 128] = p1;

  float ss = ((p0.x + p0.y) + (p0.z + p0.w)) +
             ((p1.x + p1.y) + (p1.z + p1.w));
#pragma unroll
  for (int off = 32; off > 0; off >>= 1)
    ss += __shfl_xor(ss, off, 64);
  if (lane == 0) reds[j][wslot] = ss;
  __syncthreads();   // p_lds, vidx, reds all visible

  // ---- context: quarter = t>>7 strides chunks of 4 v; d = t&127 ----
  const int qtr = t >> 7;
  const int d = t & 127;
  const int nChunks = (nv + 3) >> 2;
  float a0 = 0.f, a1 = 0.f, a2 = 0.f, a3 = 0.f;
  const float* vbase = value + b * DD + d;
  for (int ch = qtr; ch < nChunks; ch += 4) {
    int4 id = ((const int4*)vidx)[ch];
    float4 q0v = ((const float4*)&p_lds[0][0])[ch];
    float4 q1v = ((const float4*)&p_lds[1][0])[ch];
    float4 q2v = ((const float4*)&p_lds[2][0])[ch];
    float4 q3v = ((const float4*)&p_lds[3][0])[ch];
    float v0_ = vbase[(size_t)id.x * (BB * DD)];   // coalesced over d
    float v1_ = vbase[(size_t)id.y * (BB * DD)];
    float v2_ = vbase[(size_t)id.z * (BB * DD)];
    float v3_ = vbase[(size_t)id.w * (BB * DD)];
    a0 = __builtin_fmaf(q0v.x, v0_, a0); a0 = __builtin_fmaf(q0v.y, v1_, a0);
    a0 = __builtin_fmaf(q0v.z, v2_, a0); a0 = __builtin_fmaf(q0v.w, v3_, a0);
    a1 = __builtin_fmaf(q1v.x, v0_, a1); a1 = __builtin_fmaf(q1v.y, v1_, a1);
    a1 = __builtin_fmaf(q1v.z, v2_, a1); a1 = __builtin_fmaf(q1v.w, v3_, a1);
    a2 = __builtin_fmaf(q2v.x, v0_, a2); a2 = __builtin_fmaf(q2v.y, v1_, a2);
    a2 = __builtin_fmaf(q2v.z, v2_, a2); a2 = __builtin_fmaf(q2v.w, v3_, a2);
    a3 = __builtin_fmaf(q3v.x, v0_, a3); a3 = __builtin_fmaf(q3v.y, v1_, a3);
    a3 = __builtin_fmaf(q3v.z, v2_, a3); a3 = __builtin_fmaf(q3v.w, v3_, a3);
  }
  if (qtr) {
    part[qtr - 1][0][d] = a0;
    part[qtr - 1][1][d] = a1;
    part[qtr - 1][2][d] = a2;
    part[qtr - 1][3][d] = a3;
  }
  __syncthreads();
  if (qtr == 0) {
    float tot[4] = {a0, a1, a2, a3};
#pragma unroll
    for (int jj = 0; jj < 4; ++jj) {
      float s = tot[jj] + part[0][jj][d] + part[1][jj][d] + part[2][jj][d];
      float iv = 1.f / (reds[jj][0] + reds[jj][1]);
      out[((size_t)(q0 + jj) * BB + b) * DD + d] = s * iv;
    }
  }
}

extern "C" void kernel_launch(void* const* d_in, const int* in_sizes, int n_in,
                              void* d_out, int out_size, void* d_ws, size_t ws_size,
                              hipStream_t stream) {
  const float* query = (const float*)d_in[0];  // [TQ,B,D]
  const float* value = (const float*)d_in[1];  // [TV,B,D]
  const int*   mask  = (const int*)  d_in[2];  // [TV,B]
  const float* W1    = (const float*)d_in[3];  // [D,U]
  const float* W2    = (const float*)d_in[4];  // [D,U]
  const float* scale = (const float*)d_in[5];  // [U]
  float* out = (float*)d_out;

  float* Eq      = (float*)d_ws;                    // [B,TQ,U]
  float* Ek      = Eq + (size_t)BB * TQ * UU;       // [B,TV,U]
  float* scores  = Ek + (size_t)BB * TV * UU;       // [B,TQ,TV]
  int*   vidx    = (int*)(scores + (size_t)BB * TQ * TV); // [B,TV]
  int*   nvalid  = vidx + BB * TV;                  // [B]
  float* Ssum    = (float*)(nvalid + BB);           // [1]

  prep_kernel<<<BB + (TQ + TV) * BB / 8, 256, 0, stream>>>(
      query, value, W1, W2, mask, scale, Eq, Ek, vidx, nvalid, Ssum);
  scores_kernel<<<dim3(TV / 64, TQ / 16, BB), 256, 0, stream>>>(
      Eq, Ek, scale, Ssum, vidx, nvalid, scores);
  softmax_ctx_kernel<<<BB * TQ / 4, 512, 0, stream>>>(
      value, vidx, nvalid, scores, out);
}